// Round 2
// baseline (184.938 us; speedup 1.0000x reference)
//
#include <hip/hip_runtime.h>
#include <hip/hip_bf16.h>

// Problem: T=255, B=256, NIN=784, NOUT=40
// out layout: [spk_rec (255*256*40) | mem_rec (255*256*40)] fp32
#define T_STEPS 255
#define BATCH 256
#define NIN 784
#define NOUT 40
#define MROWS (T_STEPS * BATCH)          // 65280
#define TBN (T_STEPS * BATCH * NOUT)     // 2611200
#define BN_CH (BATCH * NOUT)             // 10240

#define BM 128
#define BK 112
#define LDX 116  // padded LDS row stride (dwords), multiple of 4 for float4
#define LDW 116

__global__ __launch_bounds__(256) void lif_gemm_kernel(
    const float* __restrict__ X, const float* __restrict__ W,
    float* __restrict__ cur) {
  __shared__ float xs[BM * LDX];
  __shared__ float ws[NOUT * LDW];
  const int tid = threadIdx.x;
  const int m0 = blockIdx.x * BM;
  const int tm = tid & 63;       // row within half-tile
  const int tn = tid >> 6;       // 0..3, wave-uniform
  const int nb = tn * 10;

  // fp64 accumulation: cur must be correctly-rounded fp32 so that the
  // threshold decisions (spikes) match the numpy/jax references, whose own
  // fp32 errors (~1e-6) still agree with each other (=> true margins >1e-6).
  double acc[2][10];
#pragma unroll
  for (int r = 0; r < 2; ++r)
#pragma unroll
    for (int j = 0; j < 10; ++j) acc[r][j] = 0.0;

  for (int k0 = 0; k0 < NIN; k0 += BK) {
    // stage X tile: 128 rows x 112 cols = 3584 float4 / 256 threads = 14 each
#pragma unroll
    for (int i = 0; i < 14; ++i) {
      int id = tid + i * 256;
      int row = id / 28;
      int c4 = id % 28;
      float4 v = *reinterpret_cast<const float4*>(
          X + (size_t)(m0 + row) * NIN + k0 + c4 * 4);
      *reinterpret_cast<float4*>(&xs[row * LDX + c4 * 4]) = v;
    }
    // stage W tile: 40 rows x 112 cols = 1120 float4
#pragma unroll
    for (int i = 0; i < 5; ++i) {
      int id = tid + i * 256;
      if (id < NOUT * 28) {
        int row = id / 28;
        int c4 = id % 28;
        float4 v = *reinterpret_cast<const float4*>(
            W + (size_t)row * NIN + k0 + c4 * 4);
        *reinterpret_cast<float4*>(&ws[row * LDW + c4 * 4]) = v;
      }
    }
    __syncthreads();

    for (int k4 = 0; k4 < BK; k4 += 4) {
      float4 xv0 = *reinterpret_cast<const float4*>(&xs[tm * LDX + k4]);
      float4 xv1 = *reinterpret_cast<const float4*>(&xs[(tm + 64) * LDX + k4]);
      double x0a = (double)xv0.x, x0b = (double)xv0.y,
             x0c = (double)xv0.z, x0d = (double)xv0.w;
      double x1a = (double)xv1.x, x1b = (double)xv1.y,
             x1c = (double)xv1.z, x1d = (double)xv1.w;
#pragma unroll
      for (int j = 0; j < 10; ++j) {
        float4 wv = *reinterpret_cast<const float4*>(&ws[(nb + j) * LDW + k4]);
        double wa = (double)wv.x, wb = (double)wv.y,
               wc = (double)wv.z, wd = (double)wv.w;
        acc[0][j] = fma(x0a, wa, acc[0][j]);
        acc[0][j] = fma(x0b, wb, acc[0][j]);
        acc[0][j] = fma(x0c, wc, acc[0][j]);
        acc[0][j] = fma(x0d, wd, acc[0][j]);
        acc[1][j] = fma(x1a, wa, acc[1][j]);
        acc[1][j] = fma(x1b, wb, acc[1][j]);
        acc[1][j] = fma(x1c, wc, acc[1][j]);
        acc[1][j] = fma(x1d, wd, acc[1][j]);
      }
    }
    __syncthreads();
  }

#pragma unroll
  for (int r = 0; r < 2; ++r) {
    const size_t mrow = (size_t)m0 + tm + r * 64;
#pragma unroll
    for (int j = 0; j < 10; ++j)
      cur[mrow * NOUT + nb + j] = (float)acc[r][j];
  }
}

// One thread per (b, n) chain. curmem holds cur on entry; we overwrite each
// [t] slot with mem_new after reading it (same thread, same address -> safe).
// fp32 recurrence with numpy's exact op order: t = 0.95f*mem (round),
// t + cur (round), * (1-reset) (round). asm barrier blocks fma contraction.
__global__ __launch_bounds__(256) void lif_scan_kernel(
    float* __restrict__ spk, float* __restrict__ curmem) {
  const int idx = blockIdx.x * blockDim.x + threadIdx.x;  // 0..10239
  float mem = 0.f;
  for (int t = 0; t < T_STEPS; ++t) {
    float cur = curmem[(size_t)t * BN_CH + idx];
    float reset = (mem > 1.0f) ? 1.0f : 0.0f;
    float decay = 0.95f * mem;
    asm volatile("" : "+v"(decay));  // forbid fma(0.95, mem, cur) contraction
    float summ = decay + cur;
    float mnew = summ * (1.0f - reset);
    curmem[(size_t)t * BN_CH + idx] = mnew;
    spk[(size_t)t * BN_CH + idx] = (mnew > 1.0f) ? 1.0f : 0.0f;
    mem = mnew;
  }
}

extern "C" void kernel_launch(void* const* d_in, const int* in_sizes, int n_in,
                              void* d_out, int out_size, void* d_ws,
                              size_t ws_size, hipStream_t stream) {
  (void)in_sizes; (void)n_in; (void)out_size; (void)d_ws; (void)ws_size;
  const float* X = (const float*)d_in[0];
  const float* W = (const float*)d_in[1];
  float* out = (float*)d_out;
  float* spk = out;            // [255,256,40]
  float* memout = out + TBN;   // [255,256,40], used as cur scratch then mem

  lif_gemm_kernel<<<MROWS / BM, 256, 0, stream>>>(X, W, memout);
  lif_scan_kernel<<<BN_CH / 256, 256, 0, stream>>>(spk, memout);
}

// Round 3
// 145.024 us; speedup vs baseline: 1.2752x; 1.2752x over previous
//
#include <hip/hip_runtime.h>
#include <hip/hip_bf16.h>

// Problem: T=255, B=256, NIN=784, NOUT=40
// out layout: [spk_rec (255*256*40) | mem_rec (255*256*40)] fp32
#define T_STEPS 255
#define BATCH 256
#define NIN 784
#define NOUT 40
#define MROWS (T_STEPS * BATCH)          // 65280
#define TBN (T_STEPS * BATCH * NOUT)     // 2611200
#define BN_CH (BATCH * NOUT)             // 10240

#define BM 128
#define BK 56     // 784 = 14 * 56
#define LDX 60    // padded LDS row stride (dwords); stride-60 b128 reads are
                  // conflict-free (8-lane groups cover all 32 banks)

// Convert W to fp64 once. Wd lives at the head of the spk output region
// (251 KB << 10.4 MB); the scan kernel overwrites that region afterwards.
__global__ __launch_bounds__(256) void wconv_kernel(
    const float* __restrict__ W, double* __restrict__ Wd) {
  int i = blockIdx.x * 256 + threadIdx.x;
  if (i < NOUT * NIN) Wd[i] = (double)W[i];
}

__global__ __launch_bounds__(256) void lif_gemm_kernel(
    const float* __restrict__ X, const double* __restrict__ Wd,
    float* __restrict__ cur) {
  __shared__ float xs[BM * LDX];
  const int tid = threadIdx.x;
  const int m0 = blockIdx.x * BM;
  const int tm = tid & 63;  // row within half-tile
  // wave-uniform output-column base; readfirstlane makes uniformity explicit
  // so Wd reads scalarize to s_load (no VALU, no LDS traffic for W).
  const int nbu = __builtin_amdgcn_readfirstlane((int)(threadIdx.x >> 6)) * 10;

  // fp64 accumulation, bit-identical FMA order to the validated round-2
  // kernel: cur must be correctly-rounded fp32 so threshold decisions
  // (spikes) match the numpy/jax references.
  double acc[2][10];
#pragma unroll
  for (int r = 0; r < 2; ++r)
#pragma unroll
    for (int j = 0; j < 10; ++j) acc[r][j] = 0.0;

  for (int k0 = 0; k0 < NIN; k0 += BK) {
    // stage X tile: 128 rows x 56 cols = 1792 float4 / 256 threads = 7 each
#pragma unroll
    for (int i = 0; i < 7; ++i) {
      unsigned id = tid + i * 256u;
      unsigned row = id / 14u;  // 14 float4 per row
      unsigned c4 = id % 14u;
      float4 v = *reinterpret_cast<const float4*>(
          X + (size_t)(m0 + row) * NIN + k0 + c4 * 4);
      *reinterpret_cast<float4*>(&xs[row * LDX + c4 * 4]) = v;
    }
    __syncthreads();

#pragma unroll
    for (int kk = 0; kk < BK; kk += 4) {
      float4 xv0 = *reinterpret_cast<const float4*>(&xs[tm * LDX + kk]);
      float4 xv1 = *reinterpret_cast<const float4*>(&xs[(tm + 64) * LDX + kk]);
      double x0a = (double)xv0.x, x0b = (double)xv0.y,
             x0c = (double)xv0.z, x0d = (double)xv0.w;
      double x1a = (double)xv1.x, x1b = (double)xv1.y,
             x1c = (double)xv1.z, x1d = (double)xv1.w;
      const double* wbase = Wd + (size_t)nbu * NIN + k0 + kk;
#pragma unroll
      for (int j = 0; j < 10; ++j) {
        const double* wr = wbase + (size_t)j * NIN;
        double wa = wr[0], wb = wr[1], wc = wr[2], wd = wr[3];
        acc[0][j] = fma(x0a, wa, acc[0][j]);
        acc[0][j] = fma(x0b, wb, acc[0][j]);
        acc[0][j] = fma(x0c, wc, acc[0][j]);
        acc[0][j] = fma(x0d, wd, acc[0][j]);
        acc[1][j] = fma(x1a, wa, acc[1][j]);
        acc[1][j] = fma(x1b, wb, acc[1][j]);
        acc[1][j] = fma(x1c, wc, acc[1][j]);
        acc[1][j] = fma(x1d, wd, acc[1][j]);
      }
    }
    __syncthreads();
  }

#pragma unroll
  for (int r = 0; r < 2; ++r) {
    const size_t mrow = (size_t)m0 + tm + r * 64;
#pragma unroll
    for (int j = 0; j < 10; ++j)
      cur[mrow * NOUT + nbu + j] = (float)acc[r][j];
  }
}

// One thread per (b, n) chain; 17 chunks of 15 t-steps, next chunk's cur
// loads prefetched before computing the current chunk (hides L2 latency).
// Per-step math identical to the validated round-2 scan (asm barrier blocks
// fma contraction of 0.95f*mem + cur, matching numpy's two roundings).
__global__ __launch_bounds__(64) void lif_scan_kernel(
    float* __restrict__ spk, float* __restrict__ curmem) {
  const int idx = blockIdx.x * 64 + threadIdx.x;  // 0..10239
  float mem = 0.f;
  float c[15];
#pragma unroll
  for (int i = 0; i < 15; ++i) c[i] = curmem[(size_t)i * BN_CH + idx];

  for (int ch = 0; ch < 17; ++ch) {
    const int t0 = ch * 15;
    float n[15];
    if (ch != 16) {
#pragma unroll
      for (int i = 0; i < 15; ++i)
        n[i] = curmem[(size_t)(t0 + 15 + i) * BN_CH + idx];
    }
    float m_[15], s_[15];
#pragma unroll
    for (int i = 0; i < 15; ++i) {
      float reset = (mem > 1.0f) ? 1.0f : 0.0f;
      float decay = 0.95f * mem;
      asm volatile("" : "+v"(decay));  // forbid fma contraction
      float summ = decay + c[i];
      float mnew = summ * (1.0f - reset);
      m_[i] = mnew;
      s_[i] = (mnew > 1.0f) ? 1.0f : 0.0f;
      mem = mnew;
    }
#pragma unroll
    for (int i = 0; i < 15; ++i) {
      curmem[(size_t)(t0 + i) * BN_CH + idx] = m_[i];
      spk[(size_t)(t0 + i) * BN_CH + idx] = s_[i];
    }
    if (ch != 16) {
#pragma unroll
      for (int i = 0; i < 15; ++i) c[i] = n[i];
    }
  }
}

extern "C" void kernel_launch(void* const* d_in, const int* in_sizes, int n_in,
                              void* d_out, int out_size, void* d_ws,
                              size_t ws_size, hipStream_t stream) {
  (void)in_sizes; (void)n_in; (void)out_size; (void)d_ws; (void)ws_size;
  const float* X = (const float*)d_in[0];
  const float* W = (const float*)d_in[1];
  float* out = (float*)d_out;
  float* spk = out;            // [255,256,40]
  float* memout = out + TBN;   // [255,256,40], used as cur scratch then mem
  double* Wd = (double*)out;   // 251 KB scratch at head of spk region

  wconv_kernel<<<(NOUT * NIN + 255) / 256, 256, 0, stream>>>(W, Wd);
  lif_gemm_kernel<<<MROWS / BM, 256, 0, stream>>>(X, Wd, memout);
  lif_scan_kernel<<<BN_CH / 64, 64, 0, stream>>>(spk, memout);
}